// Round 6
// baseline (3564.735 us; speedup 1.0000x reference)
//
#include <hip/hip_runtime.h>

typedef unsigned short u16;
typedef unsigned int   u32;

typedef __attribute__((ext_vector_type(8))) short bf16x8;
typedef __attribute__((ext_vector_type(16))) float f32x16;

// ---------- helpers ----------
__device__ __forceinline__ u16 f2bf(float v) {           // RNE fp32 -> bf16
    u32 u = __float_as_uint(v);
    u32 r = (u + 0x7fffu + ((u >> 16) & 1u)) >> 16;
    return (u16)r;
}
__device__ __forceinline__ float bf2f(u16 h) { return __uint_as_float(((u32)h) << 16); }

__device__ __forceinline__ float ftanh(float x) {        // tanh via exp, ~5 inst
    float e = __expf(2.0f * x);                          // inf for large x -> rcp gives 0 -> +1
    return 1.0f - 2.0f * __builtin_amdgcn_rcpf(e + 1.0f);
}

__device__ __forceinline__ void gl2lds16(const void* g, void* l) {
    __builtin_amdgcn_global_load_lds(
        (const __attribute__((address_space(1))) void*)g,
        (__attribute__((address_space(3))) void*)l, 16, 0, 0);
}

// ---------- init: zero h buffers and carry ----------
__global__ void init_k(u16* __restrict__ hh, u16* __restrict__ hl, float* __restrict__ cb) {
    int i = blockIdx.x * 256 + threadIdx.x;           // grid covers 12*512*512
    hh[i] = 0; hl[i] = 0;
    if (i < 2 * 512) cb[i] = 0.0f;
}

// ---------- pack W' with K'-interleave (K'=2304, 6 segments) + bias4 ----------
// logit = sum over K' of A'(k')*B'(k') where segments give exactly
//   ah*bh + ah*bl + al*bh   (x part, k<256)  and same for h part (k>=256).
__global__ void pack_wq(const float* __restrict__ Wf, const float* __restrict__ bf_,
                        const float* __restrict__ Wi, const float* __restrict__ bi_,
                        const float* __restrict__ Wo, const float* __restrict__ bo_,
                        const float* __restrict__ Wg, const float* __restrict__ bg_,
                        u16* __restrict__ wq, float* __restrict__ bias4) {
    int idx = blockIdx.x * 256 + threadIdx.x;         // 2048*768 threads
    int n = idx / 768, k = idx - n * 768;
    int gate = n >> 9, col = n & 511;
    const float* W = (gate == 0) ? Wf : (gate == 1) ? Wi : (gate == 2) ? Wo : Wg;
    float v = W[k * 512 + col];
    u16 h = f2bf(v);
    u16 l = f2bf(v - bf2f(h));
    size_t base = (size_t)n * 2304;
    if (k < 256) {
        wq[base + k] = h; wq[base + 512 + k] = h; wq[base + 256 + k] = l;
    } else {
        int d = k - 256;
        wq[base + 768 + d] = h; wq[base + 1792 + d] = h; wq[base + 1280 + d] = l;
    }
    if (k == 0) {
        const float* bb = (gate == 0) ? bf_ : (gate == 1) ? bi_ : (gate == 2) ? bo_ : bg_;
        bias4[n] = bb[col];
    }
}

// ---------- split ALL x to hi/lo bf16 (hoisted out of the block loop) ----------
__global__ void split_x(const float* __restrict__ src, u16* __restrict__ oh, u16* __restrict__ ol) {
    int i = blockIdx.x * 256 + threadIdx.x;           // grid covers 256*512*256/4
    float4 v = ((const float4*)src)[i];
    u16 hx = f2bf(v.x), hy = f2bf(v.y), hz = f2bf(v.z), hw = f2bf(v.w);
    u16 lx = f2bf(v.x - bf2f(hx)), ly = f2bf(v.y - bf2f(hy));
    u16 lz = f2bf(v.z - bf2f(hz)), lw = f2bf(v.w - bf2f(hw));
    uint2 hv; hv.x = (u32)hx | ((u32)hy << 16); hv.y = (u32)hz | ((u32)hw << 16);
    uint2 lv; lv.x = (u32)lx | ((u32)ly << 16); lv.y = (u32)lz | ((u32)lw << 16);
    ((uint2*)oh)[i] = hv;
    ((uint2*)ol)[i] = lv;
}

// ============================================================================
// bf16 GEMM over K'=2304, BM=192 BN=256 BK=32, 512 thr (2Mx4N waves), grid gx*8.
// A-OPERAND IN REGISTERS (global->VGPR, double-buffered 1 tile ahead; the 4
// wn-waves of a wm-group read identical lines -> L1-served; x/h slices are
// L2/L3-warm). Only B is LDS-staged (4 bufs x 16KB = 64KB). LDS traffic/tile
// drops 114KB -> 48KB (32 b128 reads + 16KB gl2lds writes) -- under the
// 775-cyc MFMA floor, so the kernel flips from LDS-BW-bound to MFMA-bound
// (r1-r5 invariant: ~2600cyc/tile at 114KB across ALL schedules).
// Per tile: vmcnt(2)[A(kt) regs ready]; issue A(kt+1) 6 loads | fence |
// B(kt+3) 2 gl2lds | fence | MFMA ks0; ds_read B(kt+1) ks0; MFMA ks1;
// ds_read B(kt+1) ks1; vmcnt(8)[retires B(kt+2) only]; s_barrier.
// Counted vmcnt never drains mid-loop; per-tile issue groups are fenced so
// FIFO counts hold regardless of in-group order.
// B LDS swizzle unchanged from r5 (SQ_LDS_BANK_CONFLICT == 0 verified).
// ============================================================================
#define KT 72
__global__ __launch_bounds__(512, 2) void gemm_q(
    const u16* __restrict__ xh, const u16* __restrict__ xl,
    const u16* __restrict__ hh, const u16* __restrict__ hl,
    const u16* __restrict__ wq, const float* __restrict__ bias4,
    float* __restrict__ lg, int Mvalid, int gx) {
    __shared__ __align__(16) u16 smem[32768];   // B: 4 x 8192 u16 (64 KiB)

    const int tid = threadIdx.x;
    const int wid = tid >> 6, lane = tid & 63;
    const int l32 = lane & 31, khalf = lane >> 5;
    const int wm = wid >> 2, wn = wid & 3;

    int bm, bn;
    if (gx == 32) { int xcd = blockIdx.x & 7, r = blockIdx.x >> 3; bm = xcd * 4 + (r & 3); bn = r >> 2; }
    else          { bm = blockIdx.x % gx; bn = blockIdx.x / gx; }

    // ---- B staging geometry: 16-row chunks, 2 gl2lds/wave/tile ----
    const int rl  = lane >> 2;                        // row in chunk 0..15
    const int bq  = lane & 3;                         // 16B block in row 0..3
    const int rlh = rl >> 3;                          // 0..1
    const int cB0 = 2 * wid, cB1 = 2 * wid + 1;       // B chunks (16)
    const size_t brow0 = (size_t)(bn * 256 + cB0 * 16 + rl) * 2304;
    const size_t brow1 = (size_t)(bn * 256 + cB1 * 16 + rl) * 2304;
    const int bk0 = (bq ^ ((2 * cB0 + rlh) & 3)) * 8; // pre-swizzled k elem offset
    const int bk1 = (bq ^ ((2 * cB1 + rlh) & 3)) * 8;
    const u32 ldsB0 = (u32)cB0 * 512 + (u32)lane * 8;
    const u32 ldsB1 = (u32)cB1 * 512 + (u32)lane * 8;

#define BB(r) ((r) * 8192)
#define STAGE_B(kt_, bo_) do {                                                \
        gl2lds16(wq + brow0 + (size_t)(kt_) * 32 + bk0, smem + (bo_) + ldsB0);\
        gl2lds16(wq + brow1 + (size_t)(kt_) * 32 + bk1, smem + (bo_) + ldsB1);\
    } while (0)

    // ---- A per-lane global offsets (u16 elems): row*str + khalf*8 ----
    u32 offx[3], offh[3];
#pragma unroll
    for (int i = 0; i < 3; ++i) {
        int row = bm * 192 + wm * 96 + i * 32 + l32;
        if (row >= Mvalid) row = Mvalid - 1;          // ragged-M clamp
        offx[i] = (u32)row * 256 + (u32)khalf * 8;
        offh[i] = (u32)row * 512 + (u32)khalf * 8;
    }

    // A frag regs: DST[0..2]=ks0 rows 0..2, DST[3..5]=ks1 (same 64B line as ks0)
#define LOADA(kt_, DST) do {                                                  \
        int k_ = (kt_);                                                       \
        if (k_ < 24) {                                                        \
            const u16* bp_ = (k_ >= 16) ? xl : xh; int ko_ = (k_ & 7) * 32;   \
            DST[0] = *(const bf16x8*)(bp_ + ko_ + offx[0]);                   \
            DST[1] = *(const bf16x8*)(bp_ + ko_ + offx[1]);                   \
            DST[2] = *(const bf16x8*)(bp_ + ko_ + offx[2]);                   \
            DST[3] = *(const bf16x8*)(bp_ + ko_ + offx[0] + 16);              \
            DST[4] = *(const bf16x8*)(bp_ + ko_ + offx[1] + 16);              \
            DST[5] = *(const bf16x8*)(bp_ + ko_ + offx[2] + 16);              \
        } else {                                                              \
            int sub_ = k_ - 24;                                               \
            const u16* bp_ = (sub_ >= 32) ? hl : hh; int ko_ = (sub_ & 15) * 32; \
            DST[0] = *(const bf16x8*)(bp_ + ko_ + offh[0]);                   \
            DST[1] = *(const bf16x8*)(bp_ + ko_ + offh[1]);                   \
            DST[2] = *(const bf16x8*)(bp_ + ko_ + offh[2]);                   \
            DST[3] = *(const bf16x8*)(bp_ + ko_ + offh[0] + 16);              \
            DST[4] = *(const bf16x8*)(bp_ + ko_ + offh[1] + 16);              \
            DST[5] = *(const bf16x8*)(bp_ + ko_ + offh[2] + 16);              \
        }                                                                     \
    } while (0)

    // ---- B fragment LDS offsets (u16 units); conflict-free swizzle folded ----
    u32 rowB[2], xk[2];
#pragma unroll
    for (int j = 0; j < 2; ++j) rowB[j] = (u32)(wn * 64 + j * 32 + l32) * 32;
#pragma unroll
    for (int ks = 0; ks < 2; ++ks) xk[ks] = (((u32)(ks * 2 + khalf)) ^ (u32)(l32 >> 3)) << 3;

    f32x16 acc[3][2];
#pragma unroll
    for (int i = 0; i < 3; ++i)
#pragma unroll
        for (int j = 0; j < 2; ++j)
#pragma unroll
            for (int r = 0; r < 16; ++r) acc[i][j][r] = 0.f;

    bf16x8 aP[6], aQ[6];                              // A double-buffer (tile parity)
    bf16x8 b00, b01, b10, b11;                        // B frags ks0/ks1

#define RD_B0(bo_) do {                                                       \
        b00 = *(const bf16x8*)(smem + (bo_) + rowB[0] + xk[0]);               \
        b01 = *(const bf16x8*)(smem + (bo_) + rowB[1] + xk[0]);               \
    } while (0)
#define RD_B1(bo_) do {                                                       \
        b10 = *(const bf16x8*)(smem + (bo_) + rowB[0] + xk[1]);               \
        b11 = *(const bf16x8*)(smem + (bo_) + rowB[1] + xk[1]);               \
    } while (0)
#define MMK(AS, k0, B0_, B1_) do {                                            \
        __builtin_amdgcn_s_setprio(1);                                        \
        acc[0][0] = __builtin_amdgcn_mfma_f32_32x32x16_bf16(AS[(k0)+0], B0_, acc[0][0], 0, 0, 0); \
        acc[0][1] = __builtin_amdgcn_mfma_f32_32x32x16_bf16(AS[(k0)+0], B1_, acc[0][1], 0, 0, 0); \
        acc[1][0] = __builtin_amdgcn_mfma_f32_32x32x16_bf16(AS[(k0)+1], B0_, acc[1][0], 0, 0, 0); \
        acc[1][1] = __builtin_amdgcn_mfma_f32_32x32x16_bf16(AS[(k0)+1], B1_, acc[1][1], 0, 0, 0); \
        acc[2][0] = __builtin_amdgcn_mfma_f32_32x32x16_bf16(AS[(k0)+2], B0_, acc[2][0], 0, 0, 0); \
        acc[2][1] = __builtin_amdgcn_mfma_f32_32x32x16_bf16(AS[(k0)+2], B1_, acc[2][1], 0, 0, 0); \
        __builtin_amdgcn_s_setprio(0);                                        \
    } while (0)

    // ---- prologue: A(0)->aP; stage B(0,1,2); wait A0,B0,B1 (keep B2 flying) ----
    LOADA(0, aP);
    __builtin_amdgcn_sched_barrier(0);
    STAGE_B(0, BB(0)); STAGE_B(1, BB(1)); STAGE_B(2, BB(2));
    asm volatile("s_waitcnt vmcnt(2)" ::: "memory");
    asm volatile("s_barrier" ::: "memory");
    __builtin_amdgcn_sched_barrier(0);
    RD_B0(BB(0)); RD_B1(BB(0));                       // tile-0 B frags

    // tile kt: CUR A-set feeds MFMAs; NXT A-set loads kt+1; RN = (kt+1)&3 B-buf
#define BODY(kt_, RN, RS, CUR, NXT) do {                                      \
        asm volatile("s_waitcnt vmcnt(2)" ::: "memory");  /* A(kt) retired */ \
        if ((kt_) + 1 < KT) LOADA((kt_) + 1, NXT);        /* 6 vmem */        \
        __builtin_amdgcn_sched_barrier(0);                                    \
        if ((kt_) + 3 < KT) STAGE_B((kt_) + 3, BB(RS));   /* 2 vmem */        \
        __builtin_amdgcn_sched_barrier(0);                                    \
        MMK(CUR, 0, b00, b01);                                                \
        if ((kt_) + 1 < KT) RD_B0(BB(RN));                                    \
        MMK(CUR, 3, b10, b11);                                                \
        if ((kt_) + 1 < KT) RD_B1(BB(RN));                                    \
        if ((kt_) < KT - 3) {                                                 \
            asm volatile("s_waitcnt vmcnt(8)" ::: "memory"); /* B(kt+2) done */\
            asm volatile("s_barrier" ::: "memory");                           \
            __builtin_amdgcn_sched_barrier(0);                                \
        } else if ((kt_) < KT - 1) {                                          \
            asm volatile("s_waitcnt vmcnt(6)" ::: "memory");                  \
            asm volatile("s_barrier" ::: "memory");                           \
            __builtin_amdgcn_sched_barrier(0);                                \
        }                                                                     \
    } while (0)

#pragma unroll 1
    for (int q = 0; q < 18; ++q) {
        int ktb = q * 4;
        BODY(ktb + 0, 1, 3, aP, aQ);
        BODY(ktb + 1, 2, 0, aQ, aP);
        BODY(ktb + 2, 3, 1, aP, aQ);
        BODY(ktb + 3, 0, 2, aQ, aP);
    }
#undef BODY
#undef STAGE_B
#undef LOADA
#undef RD_B0
#undef RD_B1
#undef MMK
#undef BB

    // C/D layout (measured): col = lane&31, row = (reg&3) + 8*(reg>>2) + 4*(lane>>5)
#pragma unroll
    for (int j = 0; j < 2; ++j) {
        int n = bn * 256 + wn * 64 + j * 32 + l32;
        float bv = bias4[n];
#pragma unroll
        for (int i = 0; i < 3; ++i) {
            int rbase = bm * 192 + wm * 96 + i * 32 + 4 * khalf;
#pragma unroll
            for (int r = 0; r < 16; ++r) {
                int row = rbase + (r & 3) + 8 * (r >> 2);
                if (row < Mvalid)
                    lg[(size_t)row * 2048 + n] = acc[i][j][r] + bv;   // via L2/L3 (gates re-reads)
            }
        }
    }
}

// ---------- one sequential chain step: r <- tanh(softmax_f[rowb]*r + softmax_i[rowb]*tanh(g[rowb])) ----------
__device__ __forceinline__ void chain_step(const float* __restrict__ lg, int j, int lane, float r[8]) {
    int rowb = (j + 1) % 12;   // batch row (t+1)%P of c_t (t0 always multiple of 12)
    const float* base = lg + (size_t)(j * 512 + rowb) * 2048 + lane * 8;
    float f[8], iv[8], g[8];
#pragma unroll
    for (int u = 0; u < 8; ++u) { f[u] = base[u]; iv[u] = base[512 + u]; g[u] = base[1536 + u]; }
    float mf = -1e30f, mi = -1e30f;
#pragma unroll
    for (int u = 0; u < 8; ++u) { mf = fmaxf(mf, f[u]); mi = fmaxf(mi, iv[u]); }
#pragma unroll
    for (int o = 32; o; o >>= 1) { mf = fmaxf(mf, __shfl_xor(mf, o)); mi = fmaxf(mi, __shfl_xor(mi, o)); }
    float sf = 0.f, si = 0.f;
#pragma unroll
    for (int u = 0; u < 8; ++u) {
        f[u] = __expf(f[u] - mf); sf += f[u];
        iv[u] = __expf(iv[u] - mi); si += iv[u];
    }
#pragma unroll
    for (int o = 32; o; o >>= 1) { sf += __shfl_xor(sf, o); si += __shfl_xor(si, o); }
    float rf = __builtin_amdgcn_rcpf(sf), ri = __builtin_amdgcn_rcpf(si);
#pragma unroll
    for (int u = 0; u < 8; ++u) {
        float gg = ftanh(g[u]);
        r[u] = ftanh(f[u] * rf * r[u] + iv[u] * ri * gg);
    }
}

// ---------- gates (chain fused): wave 0 walks chain to its block's s; then all waves do
//            softmax f,i,o + tanh g, c_new, h row (hi/lo bf16), final out ----------
__global__ __launch_bounds__(256) void gates_k(
    const float* __restrict__ lg, float* __restrict__ cb,
    u16* __restrict__ hh, u16* __restrict__ hl,
    float* __restrict__ out, int t0, int S, int rd, int wr) {
    __shared__ float rsh[512];
    const int widx = threadIdx.x >> 6, lane = threadIdx.x & 63;
    const int s = (S - 1) - (blockIdx.x >> 7);          // 128 blocks per s, longest chain first
    const int b = (blockIdx.x & 127) * 4 + widx;
    const int t = t0 + s;

    if (widx == 0) {
        float r[8];
#pragma unroll
        for (int u = 0; u < 8; ++u) r[u] = cb[rd * 512 + lane * 8 + u];
        for (int j = 0; j < s; ++j) chain_step(lg, j, lane, r);   // identical op sequence in every block -> bitwise-identical r
#pragma unroll
        for (int u = 0; u < 8; ++u) rsh[lane * 8 + u] = r[u];
        // carrier block (s == S-1, early dispatch) extends the chain one step, writes next-launch carry
        if ((int)blockIdx.x == 127 && t0 + S < 256) {
            chain_step(lg, S - 1, lane, r);
#pragma unroll
            for (int u = 0; u < 8; ++u) cb[wr * 512 + lane * 8 + u] = r[u];
        }
    }
    __syncthreads();

    const float* row = lg + (size_t)(s * 512 + b) * 2048 + lane * 8;
    float f[8], iv[8], ov[8], g[8];
#pragma unroll
    for (int u = 0; u < 8; ++u) {
        f[u] = row[u]; iv[u] = row[512 + u]; ov[u] = row[1024 + u]; g[u] = row[1536 + u];
    }
    float mf = -1e30f, mi = -1e30f, mo = -1e30f;
#pragma unroll
    for (int u = 0; u < 8; ++u) { mf = fmaxf(mf, f[u]); mi = fmaxf(mi, iv[u]); mo = fmaxf(mo, ov[u]); }
#pragma unroll
    for (int o = 32; o; o >>= 1) {
        mf = fmaxf(mf, __shfl_xor(mf, o));
        mi = fmaxf(mi, __shfl_xor(mi, o));
        mo = fmaxf(mo, __shfl_xor(mo, o));
    }
    float sf = 0.f, si = 0.f, so = 0.f;
#pragma unroll
    for (int u = 0; u < 8; ++u) {
        f[u] = __expf(f[u] - mf); sf += f[u];
        iv[u] = __expf(iv[u] - mi); si += iv[u];
        ov[u] = __expf(ov[u] - mo); so += ov[u];
    }
#pragma unroll
    for (int o = 32; o; o >>= 1) {
        sf += __shfl_xor(sf, o); si += __shfl_xor(si, o); so += __shfl_xor(so, o);
    }
    float rf = __builtin_amdgcn_rcpf(sf), ri = __builtin_amdgcn_rcpf(si), ro = __builtin_amdgcn_rcpf(so);
    float hout[8];
#pragma unroll
    for (int u = 0; u < 8; ++u) {
        float rr = rsh[lane * 8 + u];
        float gg = ftanh(g[u]);
        float cv = ftanh(f[u] * rf * rr + iv[u] * ri * gg);
        hout[u] = ov[u] * ro * cv;
    }
    u32 hhp[4], hlp[4];
#pragma unroll
    for (int u = 0; u < 4; ++u) {
        u16 h0 = f2bf(hout[2 * u]), h1 = f2bf(hout[2 * u + 1]);
        u16 l0 = f2bf(hout[2 * u] - bf2f(h0)), l1 = f2bf(hout[2 * u + 1] - bf2f(h1));
        hhp[u] = (u32)h0 | ((u32)h1 << 16);
        hlp[u] = (u32)l0 | ((u32)l1 << 16);
    }
    size_t hb = ((size_t)(s * 512 + b)) * 512 + lane * 8;   // h row index = t%12 = s
    *(uint4*)&hh[hb] = make_uint4(hhp[0], hhp[1], hhp[2], hhp[3]);
    *(uint4*)&hl[hb] = make_uint4(hlp[0], hlp[1], hlp[2], hlp[3]);
    if (t == 255) {
        float* op = out + (size_t)b * 512 + lane * 8;
#pragma unroll
        for (int u = 0; u < 8; ++u) op[u] = hout[u];
    }
}

extern "C" void kernel_launch(void* const* d_in, const int* in_sizes, int n_in,
                              void* d_out, int out_size, void* d_ws, size_t ws_size,
                              hipStream_t stream) {
    const float* x   = (const float*)d_in[0];
    const float* Wf  = (const float*)d_in[1];
    const float* bf_ = (const float*)d_in[2];
    const float* Wi  = (const float*)d_in[3];
    const float* bi_ = (const float*)d_in[4];
    const float* Wo  = (const float*)d_in[5];
    const float* bo_ = (const float*)d_in[6];
    const float* Wg  = (const float*)d_in[7];
    const float* bg_ = (const float*)d_in[8];
    float* out = (float*)d_out;

    char* p = (char*)d_ws;
    u16* xh  = (u16*)p; p += 134217728;     // [256*512, 256] bf16 hi (full sequence)
    u16* xl  = (u16*)p; p += 134217728;
    u16* wq  = (u16*)p; p += 9437184;       // [2048, 2304] K'-interleaved W'
    u16* hh  = (u16*)p; p += 6291456;       // [12, 512, 512] bf16 hi
    u16* hl  = (u16*)p; p += 6291456;
    float* bias4 = (float*)p; p += 8192;    // [2048]
    float* cb    = (float*)p; p += 4096;    // [2][512] carry double-buffer
    float* lg    = (float*)p; p += 50331648;// [12*512, 2048] fp32 logits
    // total ~341 MiB (ws poison shows 512 MiB available)

    init_k<<<12288, 256, 0, stream>>>(hh, hl, cb);
    pack_wq<<<6144, 256, 0, stream>>>(Wf, bf_, Wi, bi_, Wo, bo_, Wg, bg_, wq, bias4);
    split_x<<<32768, 256, 0, stream>>>(x, xh, xl);

    for (int blk = 0; blk < 22; ++blk) {
        int t0 = blk * 12;
        int S = (256 - t0 >= 12) ? 12 : (256 - t0);  // last block: 4 steps
        int M = S * 512;
        int gx = (M + 191) / 192;                    // S=12 -> 32 (exact), S=4 -> 11 (ragged)
        gemm_q<<<gx * 8, 512, 0, stream>>>(
            xh + (size_t)t0 * 512 * 256, xl + (size_t)t0 * 512 * 256,
            hh, hl, wq, bias4, lg, M, gx);
        gates_k<<<S * 128, 256, 0, stream>>>(lg, cb, hh, hl, out, t0, S, blk & 1, (blk + 1) & 1);
    }
}

// Round 8
// 2007.453 us; speedup vs baseline: 1.7758x; 1.7758x over previous
//
#include <hip/hip_runtime.h>

typedef unsigned short u16;
typedef unsigned int   u32;

typedef __attribute__((ext_vector_type(8))) short bf16x8;
typedef __attribute__((ext_vector_type(4))) float f32x4;

// ---------- helpers ----------
__device__ __forceinline__ u16 f2bf(float v) {           // RNE fp32 -> bf16
    u32 u = __float_as_uint(v);
    u32 r = (u + 0x7fffu + ((u >> 16) & 1u)) >> 16;
    return (u16)r;
}
__device__ __forceinline__ float bf2f(u16 h) { return __uint_as_float(((u32)h) << 16); }

__device__ __forceinline__ float ftanh(float x) {        // tanh via exp, ~5 inst
    float e = __expf(2.0f * x);                          // inf for large x -> rcp gives 0 -> +1
    return 1.0f - 2.0f * __builtin_amdgcn_rcpf(e + 1.0f);
}

__device__ __forceinline__ void gl2lds16(const void* g, void* l) {
    __builtin_amdgcn_global_load_lds(
        (const __attribute__((address_space(1))) void*)g,
        (__attribute__((address_space(3))) void*)l, 16, 0, 0);
}

// ---------- init: zero h buffers and carry ----------
__global__ void init_k(u16* __restrict__ hh, u16* __restrict__ hl, float* __restrict__ cb) {
    int i = blockIdx.x * 256 + threadIdx.x;           // grid covers 12*512*512
    hh[i] = 0; hl[i] = 0;
    if (i < 2 * 512) cb[i] = 0.0f;
}

// ---------- pack W' with K'-interleave (K'=2304, 6 segments) + bias4 ----------
// logit = sum over K' of A'(k')*B'(k'): segments give exactly
//   ah*bh + ah*bl + al*bh   (x part, k<256)  and same for h part (k>=256).
__global__ void pack_wq(const float* __restrict__ Wf, const float* __restrict__ bf_,
                        const float* __restrict__ Wi, const float* __restrict__ bi_,
                        const float* __restrict__ Wo, const float* __restrict__ bo_,
                        const float* __restrict__ Wg, const float* __restrict__ bg_,
                        u16* __restrict__ wq, float* __restrict__ bias4) {
    int idx = blockIdx.x * 256 + threadIdx.x;         // 2048*768 threads
    int n = idx / 768, k = idx - n * 768;
    int gate = n >> 9, col = n & 511;
    const float* W = (gate == 0) ? Wf : (gate == 1) ? Wi : (gate == 2) ? Wo : Wg;
    float v = W[k * 512 + col];
    u16 h = f2bf(v);
    u16 l = f2bf(v - bf2f(h));
    size_t base = (size_t)n * 2304;
    if (k < 256) {
        wq[base + k] = h; wq[base + 512 + k] = h; wq[base + 256 + k] = l;
    } else {
        int d = k - 256;
        wq[base + 768 + d] = h; wq[base + 1792 + d] = h; wq[base + 1280 + d] = l;
    }
    if (k == 0) {
        const float* bb = (gate == 0) ? bf_ : (gate == 1) ? bi_ : (gate == 2) ? bo_ : bg_;
        bias4[n] = bb[col];
    }
}

// ---------- split ALL x to hi/lo bf16 (hoisted out of the block loop) ----------
__global__ void split_x(const float* __restrict__ src, u16* __restrict__ oh, u16* __restrict__ ol) {
    int i = blockIdx.x * 256 + threadIdx.x;           // grid covers 256*512*256/4
    float4 v = ((const float4*)src)[i];
    u16 hx = f2bf(v.x), hy = f2bf(v.y), hz = f2bf(v.z), hw = f2bf(v.w);
    u16 lx = f2bf(v.x - bf2f(hx)), ly = f2bf(v.y - bf2f(hy));
    u16 lz = f2bf(v.z - bf2f(hz)), lw = f2bf(v.w - bf2f(hw));
    uint2 hv; hv.x = (u32)hx | ((u32)hy << 16); hv.y = (u32)hz | ((u32)hw << 16);
    uint2 lv; lv.x = (u32)lx | ((u32)ly << 16); lv.y = (u32)lz | ((u32)lw << 16);
    ((uint2*)oh)[i] = hv;
    ((uint2*)ol)[i] = lv;
}

// ============================================================================
// m201-faithful 8-phase GEMM. BM=BN=256, BK=64, 512 thr (2Mx4N waves, wave-tile
// 128x64), 16x16x32 MFMA, LDS 2x64KB dbuf. grid = (M/256)*8 (M%256==0 always).
// Per K-tile, 4 phases (16 MFMA each = one (M-half, ks) cell over full wave-N):
//   p0: stage B0(kt+1) | 8 ds_read (A-h0-ks0 + B-ks0) | bar | 16 MFMA |
//       vmcnt(2) | bar   <- publishes A1(kt)
//   p1: stage B1(kt+1) | 4 ds_read (A-h1-ks0)         | bar | 16 MFMA | bar
//   p2: stage A0(kt+1) | 8 ds_read (A-h0-ks1 + B-ks1) | bar | 16 MFMA | bar
//   p3: stage A1(kt+1) | 4 ds_read (A-h1-ks1)         | bar | 16 MFMA |
//       vmcnt(2) | bar   <- publishes B0,B1,A0(kt+1)
// Counted vmcnt NEVER drains mid-loop; steady-state invariant: A1(kt)
// outstanding at tile entry (FIFO-verified periodic). Staged units are 16KB
// (2 gl2lds/thread): B0=cols 0-127, B1=128-255; A wm-interleaved so each
// phase's readers touch only published units: A0={rows 0-63,128-191},
// A1={64-127,192-255}.
// LDS swizzle: slot s holds k-chunk s^(row&7) (source-side pre-swizzle for
// gl2lds, dest stays lane-linear); frag reads fold the same XOR -> per-instr
// 8 dwords/bank uniform = conflict-free (bank math checked).
// ============================================================================
#define KT 36
__global__ __launch_bounds__(512, 2) void gemm_q(
    const u16* __restrict__ xh, const u16* __restrict__ xl,
    const u16* __restrict__ hh, const u16* __restrict__ hl,
    const u16* __restrict__ wq, const float* __restrict__ bias4,
    float* __restrict__ lg, int gx) {
    __shared__ __align__(16) u16 smem[65536];   // 2 bufs x 32768 u16 (128 KiB)

    const int tid = threadIdx.x;
    const int wid = tid >> 6, lane = tid & 63;
    const int l15 = lane & 15, l4 = lane >> 4;
    const int wm = wid >> 2, wn = wid & 3;

    // XCD rect: xcd owns (gx/8) bm x 8 bn (gx=24 -> 3x8; gx=8 -> 1x8)
    const int xcd = blockIdx.x & 7, rr_ = blockIdx.x >> 3;
    const int bmp = gx >> 3;
    const int bm = xcd * bmp + (rr_ % bmp);
    const int bn = rr_ / bmp;

    // ---- staging precomputes: per thread, 2 loads per 16KB unit ----
    // idx = q*512+tid; ro = idx>>3 (0..127), s = idx&7, chunk c = s^(ro&7)
    u32 aox[2][2], aoh[2][2], adst[2][2];   // [unit][q], elem offsets
    u32 boff[2][2], bdst[2][2];
#pragma unroll
    for (int q = 0; q < 2; ++q) {
        u32 idx = (u32)q * 512 + (u32)tid;
        u32 ro = idx >> 3, s = idx & 7, c = s ^ (ro & 7);
#pragma unroll
        for (int u = 0; u < 2; ++u) {
            u32 arow = (u32)bm * 256 + (ro & 63) + (ro >> 6) * 128 + (u32)u * 64;
            u32 alds = ((ro & 63) + (ro >> 6) * 128 + (u32)u * 64) * 64 + s * 8;
            aox[u][q] = arow * 256 + c * 8;
            aoh[u][q] = arow * 512 + c * 8;
            adst[u][q] = alds;
            u32 bcol = (u32)bn * 256 + (u32)u * 128 + ro;
            boff[u][q] = bcol * 2304 + c * 8;
            bdst[u][q] = 16384 + ((u32)u * 128 + ro) * 64 + s * 8;
        }
    }

    // ---- fragment read offsets (u16 units); swizzle folded ----
    u32 rA[8], rB[4], sK[2];
#pragma unroll
    for (int f = 0; f < 8; ++f) rA[f] = (u32)(wm * 128 + f * 16 + l15) * 64;
#pragma unroll
    for (int f = 0; f < 4; ++f) rB[f] = 16384u + (u32)(wn * 64 + f * 16 + l15) * 64;
#pragma unroll
    for (int ks = 0; ks < 2; ++ks) sK[ks] = (u32)(((ks * 4 + l4) ^ (lane & 7)) * 8);

    f32x4 acc[8][4];
#pragma unroll
    for (int f = 0; f < 8; ++f)
#pragma unroll
        for (int j = 0; j < 4; ++j) { acc[f][j].x = 0.f; acc[f][j].y = 0.f; acc[f][j].z = 0.f; acc[f][j].w = 0.f; }

    bf16x8 aH[4], bF[4];

#define STAGE_B(u) do {                                                       \
        gl2lds16(bsr + boff[u][0], smem + nb32 + bdst[u][0]);                 \
        gl2lds16(bsr + boff[u][1], smem + nb32 + bdst[u][1]); } while (0)
#define STAGE_A(u) do {                                                       \
        gl2lds16(as_ + (xp ? aox[u][0] : aoh[u][0]) + ako, smem + nb32 + adst[u][0]); \
        gl2lds16(as_ + (xp ? aox[u][1] : aoh[u][1]) + ako, smem + nb32 + adst[u][1]); } while (0)
#define RD_A(h, ks) do {                                                      \
        aH[0] = *(const bf16x8*)(smem + cb32 + rA[(h)*4+0] + sK[ks]);         \
        aH[1] = *(const bf16x8*)(smem + cb32 + rA[(h)*4+1] + sK[ks]);         \
        aH[2] = *(const bf16x8*)(smem + cb32 + rA[(h)*4+2] + sK[ks]);         \
        aH[3] = *(const bf16x8*)(smem + cb32 + rA[(h)*4+3] + sK[ks]); } while (0)
#define RD_B(ks) do {                                                         \
        bF[0] = *(const bf16x8*)(smem + cb32 + rB[0] + sK[ks]);               \
        bF[1] = *(const bf16x8*)(smem + cb32 + rB[1] + sK[ks]);               \
        bF[2] = *(const bf16x8*)(smem + cb32 + rB[2] + sK[ks]);               \
        bF[3] = *(const bf16x8*)(smem + cb32 + rB[3] + sK[ks]); } while (0)
#define MM16(hb) do {                                                         \
        __builtin_amdgcn_s_setprio(1);                                        \
        _Pragma("unroll")                                                     \
        for (int fi_ = 0; fi_ < 4; ++fi_)                                     \
            _Pragma("unroll")                                                 \
            for (int fj_ = 0; fj_ < 4; ++fj_)                                 \
                acc[(hb)*4+fi_][fj_] = __builtin_amdgcn_mfma_f32_16x16x32_bf16(\
                    aH[fi_], bF[fj_], acc[(hb)*4+fi_][fj_], 0, 0, 0);         \
        __builtin_amdgcn_s_setprio(0);                                        \
    } while (0)
#define BAR() do { __builtin_amdgcn_s_barrier(); __builtin_amdgcn_sched_barrier(0); } while (0)

    // ---- prologue: stage tile 0 (order B0,B1,A0,A1 = steady retire order) ----
    {
        const int nb32 = 0;
        const u16* bsr = wq;                      // kn = 0
        const u16* as_ = xh; const u32 ako = 0; const bool xp = true;
        STAGE_B(0); STAGE_B(1); STAGE_A(0); STAGE_A(1);
    }
    asm volatile("s_waitcnt vmcnt(2)" ::: "memory");  // A1(0) stays in flight
    BAR();

#pragma unroll 2
    for (int kt = 0; kt < KT; ++kt) {
        const int cb32 = (kt & 1) << 15;
        const int nb32 = cb32 ^ 32768;
        const int kn = kt + 1;
        const bool stg = (kn < KT);
        const u16* as_ = xh; u32 ako = 0; bool xp = true;
        if (stg) {
            if (kn < 12) { as_ = (kn >= 8) ? xl : xh; ako = (u32)(kn & 3) * 64; xp = true; }
            else { int s2 = kn - 12; as_ = (s2 >= 16) ? hl : hh; ako = (u32)(s2 & 7) * 64; xp = false; }
        }
        const u16* bsr = wq + (size_t)kn * 64;

        // ---- p0: (h0, ks0) ----
        if (stg) STAGE_B(0);
        RD_B(0); RD_A(0, 0);
        BAR();
        MM16(0);
        if (stg) asm volatile("s_waitcnt vmcnt(2)" ::: "memory");  // publish A1(kt)
        else     asm volatile("s_waitcnt vmcnt(0)" ::: "memory");  // final drain
        BAR();
        // ---- p1: (h1, ks0) ----
        if (stg) STAGE_B(1);
        RD_A(1, 0);
        BAR();
        MM16(1);
        BAR();
        // ---- p2: (h0, ks1) ----
        if (stg) STAGE_A(0);
        RD_B(1); RD_A(0, 1);
        BAR();
        MM16(0);
        BAR();
        // ---- p3: (h1, ks1) ----
        if (stg) STAGE_A(1);
        RD_A(1, 1);
        BAR();
        MM16(1);
        if (stg) asm volatile("s_waitcnt vmcnt(2)" ::: "memory");  // publish B0,B1,A0(kt+1)
        BAR();
    }
#undef STAGE_B
#undef STAGE_A
#undef RD_A
#undef RD_B
#undef MM16
#undef BAR

    // C/D layout (16x16): col = lane&15, row = (lane>>4)*4 + reg
#pragma unroll
    for (int fj = 0; fj < 4; ++fj) {
        int n = bn * 256 + wn * 64 + fj * 16 + l15;
        float bv = bias4[n];
#pragma unroll
        for (int f = 0; f < 8; ++f) {
            int row = bm * 256 + wm * 128 + f * 16 + l4 * 4;
            lg[(size_t)(row + 0) * 2048 + n] = acc[f][fj].x + bv;
            lg[(size_t)(row + 1) * 2048 + n] = acc[f][fj].y + bv;
            lg[(size_t)(row + 2) * 2048 + n] = acc[f][fj].z + bv;
            lg[(size_t)(row + 3) * 2048 + n] = acc[f][fj].w + bv;
        }
    }
}

// ---------- one sequential chain step: r <- tanh(softmax_f[rowb]*r + softmax_i[rowb]*tanh(g[rowb])) ----------
__device__ __forceinline__ void chain_step(const float* __restrict__ lg, int j, int lane, float r[8]) {
    int rowb = (j + 1) % 12;   // batch row (t+1)%P of c_t (t0 always multiple of 12)
    const float* base = lg + (size_t)(j * 512 + rowb) * 2048 + lane * 8;
    float f[8], iv[8], g[8];
#pragma unroll
    for (int u = 0; u < 8; ++u) { f[u] = base[u]; iv[u] = base[512 + u]; g[u] = base[1536 + u]; }
    float mf = -1e30f, mi = -1e30f;
#pragma unroll
    for (int u = 0; u < 8; ++u) { mf = fmaxf(mf, f[u]); mi = fmaxf(mi, iv[u]); }
#pragma unroll
    for (int o = 32; o; o >>= 1) { mf = fmaxf(mf, __shfl_xor(mf, o)); mi = fmaxf(mi, __shfl_xor(mi, o)); }
    float sf = 0.f, si = 0.f;
#pragma unroll
    for (int u = 0; u < 8; ++u) {
        f[u] = __expf(f[u] - mf); sf += f[u];
        iv[u] = __expf(iv[u] - mi); si += iv[u];
    }
#pragma unroll
    for (int o = 32; o; o >>= 1) { sf += __shfl_xor(sf, o); si += __shfl_xor(si, o); }
    float rf = __builtin_amdgcn_rcpf(sf), ri = __builtin_amdgcn_rcpf(si);
#pragma unroll
    for (int u = 0; u < 8; ++u) {
        float gg = ftanh(g[u]);
        r[u] = ftanh(f[u] * rf * r[u] + iv[u] * ri * gg);
    }
}

// ---------- gates (chain fused): wave 0 walks chain to its block's s; then all waves do
//            softmax f,i,o + tanh g, c_new, h row (hi/lo bf16), final out ----------
__global__ __launch_bounds__(256) void gates_k(
    const float* __restrict__ lg, float* __restrict__ cb,
    u16* __restrict__ hh, u16* __restrict__ hl,
    float* __restrict__ out, int t0, int S, int rd, int wr) {
    __shared__ float rsh[512];
    const int widx = threadIdx.x >> 6, lane = threadIdx.x & 63;
    const int s = (S - 1) - (blockIdx.x >> 7);          // 128 blocks per s, longest chain first
    const int b = (blockIdx.x & 127) * 4 + widx;
    const int t = t0 + s;

    if (widx == 0) {
        float r[8];
#pragma unroll
        for (int u = 0; u < 8; ++u) r[u] = cb[rd * 512 + lane * 8 + u];
        for (int j = 0; j < s; ++j) chain_step(lg, j, lane, r);   // identical op sequence in every block -> bitwise-identical r
#pragma unroll
        for (int u = 0; u < 8; ++u) rsh[lane * 8 + u] = r[u];
        // carrier block (s == S-1, early dispatch) extends the chain one step, writes next-launch carry
        if ((int)blockIdx.x == 127 && t0 + S < 256) {
            chain_step(lg, S - 1, lane, r);
#pragma unroll
            for (int u = 0; u < 8; ++u) cb[wr * 512 + lane * 8 + u] = r[u];
        }
    }
    __syncthreads();

    const float* row = lg + (size_t)(s * 512 + b) * 2048 + lane * 8;
    float f[8], iv[8], ov[8], g[8];
#pragma unroll
    for (int u = 0; u < 8; ++u) {
        f[u] = row[u]; iv[u] = row[512 + u]; ov[u] = row[1024 + u]; g[u] = row[1536 + u];
    }
    float mf = -1e30f, mi = -1e30f, mo = -1e30f;
#pragma unroll
    for (int u = 0; u < 8; ++u) { mf = fmaxf(mf, f[u]); mi = fmaxf(mi, iv[u]); mo = fmaxf(mo, ov[u]); }
#pragma unroll
    for (int o = 32; o; o >>= 1) {
        mf = fmaxf(mf, __shfl_xor(mf, o));
        mi = fmaxf(mi, __shfl_xor(mi, o));
        mo = fmaxf(mo, __shfl_xor(mo, o));
    }
    float sf = 0.f, si = 0.f, so = 0.f;
#pragma unroll
    for (int u = 0; u < 8; ++u) {
        f[u] = __expf(f[u] - mf); sf += f[u];
        iv[u] = __expf(iv[u] - mi); si += iv[u];
        ov[u] = __expf(ov[u] - mo); so += ov[u];
    }
#pragma unroll
    for (int o = 32; o; o >>= 1) {
        sf += __shfl_xor(sf, o); si += __shfl_xor(si, o); so += __shfl_xor(so, o);
    }
    float rf = __builtin_amdgcn_rcpf(sf), ri = __builtin_amdgcn_rcpf(si), ro = __builtin_amdgcn_rcpf(so);
    float hout[8];
#pragma unroll
    for (int u = 0; u < 8; ++u) {
        float rr = rsh[lane * 8 + u];
        float gg = ftanh(g[u]);
        float cv = ftanh(f[u] * rf * rr + iv[u] * ri * gg);
        hout[u] = ov[u] * ro * cv;
    }
    u32 hhp[4], hlp[4];
#pragma unroll
    for (int u = 0; u < 4; ++u) {
        u16 h0 = f2bf(hout[2 * u]), h1 = f2bf(hout[2 * u + 1]);
        u16 l0 = f2bf(hout[2 * u] - bf2f(h0)), l1 = f2bf(hout[2 * u + 1] - bf2f(h1));
        hhp[u] = (u32)h0 | ((u32)h1 << 16);
        hlp[u] = (u32)l0 | ((u32)l1 << 16);
    }
    size_t hb = ((size_t)(s * 512 + b)) * 512 + lane * 8;   // h row index = t%12 = s
    *(uint4*)&hh[hb] = make_uint4(hhp[0], hhp[1], hhp[2], hhp[3]);
    *(uint4*)&hl[hb] = make_uint4(hlp[0], hlp[1], hlp[2], hlp[3]);
    if (t == 255) {
        float* op = out + (size_t)b * 512 + lane * 8;
#pragma unroll
        for (int u = 0; u < 8; ++u) op[u] = hout[u];
    }
}

extern "C" void kernel_launch(void* const* d_in, const int* in_sizes, int n_in,
                              void* d_out, int out_size, void* d_ws, size_t ws_size,
                              hipStream_t stream) {
    const float* x   = (const float*)d_in[0];
    const float* Wf  = (const float*)d_in[1];
    const float* bf_ = (const float*)d_in[2];
    const float* Wi  = (const float*)d_in[3];
    const float* bi_ = (const float*)d_in[4];
    const float* Wo  = (const float*)d_in[5];
    const float* bo_ = (const float*)d_in[6];
    const float* Wg  = (const float*)d_in[7];
    const float* bg_ = (const float*)d_in[8];
    float* out = (float*)d_out;

    char* p = (char*)d_ws;
    u16* xh  = (u16*)p; p += 134217728;     // [256*512, 256] bf16 hi (full sequence)
    u16* xl  = (u16*)p; p += 134217728;
    u16* wq  = (u16*)p; p += 9437184;       // [2048, 2304] K'-interleaved W'
    u16* hh  = (u16*)p; p += 6291456;       // [12, 512, 512] bf16 hi
    u16* hl  = (u16*)p; p += 6291456;
    float* bias4 = (float*)p; p += 8192;    // [2048]
    float* cb    = (float*)p; p += 4096;    // [2][512] carry double-buffer
    float* lg    = (float*)p; p += 50331648;// [12*512, 2048] fp32 logits
    // total ~341 MiB (ws poison shows 512 MiB available)

    init_k<<<12288, 256, 0, stream>>>(hh, hl, cb);
    pack_wq<<<6144, 256, 0, stream>>>(Wf, bf_, Wi, bi_, Wo, bo_, Wg, bg_, wq, bias4);
    split_x<<<32768, 256, 0, stream>>>(x, xh, xl);

    for (int blk = 0; blk < 22; ++blk) {
        int t0 = blk * 12;
        int S = (256 - t0 >= 12) ? 12 : (256 - t0);  // last block: 4 steps
        int M = S * 512;                             // 6144 or 2048: both % 256 == 0
        int gx = M / 256;                            // 24 or 8
        gemm_q<<<gx * 8, 512, 0, stream>>>(
            xh + (size_t)t0 * 512 * 256, xl + (size_t)t0 * 512 * 256,
            hh, hl, wq, bias4, lg, gx);
        gates_k<<<S * 128, 256, 0, stream>>>(lg, cb, hh, hl, out, t0, S, blk & 1, (blk + 1) & 1);
    }
}